// Round 1
// baseline (525.280 us; speedup 1.0000x reference)
//
#include <hip/hip_runtime.h>
#include <stdint.h>

typedef unsigned short u16;
typedef __attribute__((ext_vector_type(8))) short bf16x8;
typedef __attribute__((ext_vector_type(4))) float f32x4;

#define T_TOK 4096
#define D_DIM 1024
#define F_DIM 2048
#define NEXP 8
#define BM 128
#define BK 64
#define NDESC 112

struct Desc { int row_start; int nrows; int e; int pad; };

__device__ __forceinline__ u16 f2bf(float x) {
  union { float f; unsigned u; } v; v.f = x;
  unsigned r = v.u + 0x7FFFu + ((v.u >> 16) & 1u);
  return (u16)(r >> 16);
}
__device__ __forceinline__ float bf2f(u16 b) {
  union { unsigned u; float f; } v; v.u = ((unsigned)b) << 16;
  return v.f;
}

#define GLD16(g, l) __builtin_amdgcn_global_load_lds( \
    (const __attribute__((address_space(1))) unsigned int*)(const void*)(g), \
    (__attribute__((address_space(3))) unsigned int*)(void*)(l), 16, 0, 0)

// ---------------- elementwise convert f32 -> bf16 ----------------
__global__ void k_convert(const float* __restrict__ src, u16* __restrict__ dst, int n8) {
  int i = blockIdx.x * blockDim.x + threadIdx.x;
  if (i >= n8) return;
  const float4* s = (const float4*)src + (size_t)i * 2;
  float4 a = s[0], b = s[1];
  u16 o[8] = {f2bf(a.x), f2bf(a.y), f2bf(a.z), f2bf(a.w),
              f2bf(b.x), f2bf(b.y), f2bf(b.z), f2bf(b.w)};
  *(uint4*)(dst + (size_t)i * 8) = *(const uint4*)o;
}

// ---------- convert + transpose: src [R][C] f32 -> dst [C][R] bf16 ----------
__global__ void k_tconv(const float* __restrict__ src, u16* __restrict__ dst, int R, int C) {
  size_t mo = (size_t)blockIdx.z * R * C;
  src += mo; dst += mo;
  const int rb = blockIdx.x * 64, cb = blockIdx.y * 64;
  __shared__ u16 tile[64][72];
  const int tid = threadIdx.x;
  const int lr = tid >> 4, lc = (tid & 15) * 4;
  #pragma unroll
  for (int p = 0; p < 4; p++) {
    int r = p * 16 + lr;
    float4 v = *(const float4*)(src + (size_t)(rb + r) * C + cb + lc);
    tile[r][lc + 0] = f2bf(v.x); tile[r][lc + 1] = f2bf(v.y);
    tile[r][lc + 2] = f2bf(v.z); tile[r][lc + 3] = f2bf(v.w);
  }
  __syncthreads();
  #pragma unroll
  for (int it = 0; it < 2; it++) {
    int chunk = it * 256 + tid;          // 0..511
    int c = chunk >> 3, r0 = (chunk & 7) * 8;
    u16 o[8];
    #pragma unroll
    for (int i = 0; i < 8; i++) o[i] = tile[r0 + i][c];
    *(uint4*)(dst + (size_t)(cb + c) * R + rb + r0) = *(const uint4*)o;
  }
}

// ---------------- router: fp32 logits, softmax, top-2, re-softmax ----------------
__global__ void k_router(const float* __restrict__ X, const float* __restrict__ Wr,
                         int* __restrict__ tk_idx, float* __restrict__ tk_w,
                         int* __restrict__ counts) {
  const int w = threadIdx.x >> 6, lane = threadIdx.x & 63;
  const int t = blockIdx.x * 4 + w;
  float acc[8] = {0.f, 0.f, 0.f, 0.f, 0.f, 0.f, 0.f, 0.f};
  const float* xr = X + (size_t)t * D_DIM;
  for (int i = lane; i < D_DIM; i += 64) {
    float x = xr[i];
    const float4* wrp = (const float4*)(Wr + (size_t)i * 8);
    float4 w0 = wrp[0], w1 = wrp[1];
    acc[0] += x * w0.x; acc[1] += x * w0.y; acc[2] += x * w0.z; acc[3] += x * w0.w;
    acc[4] += x * w1.x; acc[5] += x * w1.y; acc[6] += x * w1.z; acc[7] += x * w1.w;
  }
  #pragma unroll
  for (int m = 32; m; m >>= 1) {
    #pragma unroll
    for (int e = 0; e < 8; e++) acc[e] += __shfl_xor(acc[e], m);
  }
  float mx = acc[0];
  #pragma unroll
  for (int e = 1; e < 8; e++) mx = fmaxf(mx, acc[e]);
  float p[8], Z = 0.f;
  #pragma unroll
  for (int e = 0; e < 8; e++) { p[e] = expf(acc[e] - mx); Z += p[e]; }
  float inv = 1.f / Z;
  #pragma unroll
  for (int e = 0; e < 8; e++) p[e] *= inv;
  int e1 = 0; float p1 = p[0];
  #pragma unroll
  for (int e = 1; e < 8; e++) if (p[e] > p1) { p1 = p[e]; e1 = e; }
  int e2 = -1; float p2 = -1.f;
  #pragma unroll
  for (int e = 0; e < 8; e++) if (e != e1 && p[e] > p2) { p2 = p[e]; e2 = e; }
  float bb = expf(p2 - p1);
  float w1v = 1.f / (1.f + bb), w2v = 1.f - w1v;
  if (lane == 0) {
    tk_idx[t * 2] = e1; tk_idx[t * 2 + 1] = e2;
    tk_w[t * 2] = w1v;  tk_w[t * 2 + 1] = w2v;
    atomicAdd(&counts[e1], 1); atomicAdd(&counts[e2], 1);
  }
}

__global__ void k_zmeta(int* m) { if (threadIdx.x < 32) m[threadIdx.x] = 0; }

// ---------------- scan + tile descriptors (single thread; tiny) ----------------
__global__ void k_scan(const int* __restrict__ counts, int* __restrict__ offsets,
                       int* __restrict__ cursors, Desc* __restrict__ descs) {
  if (threadIdx.x != 0) return;
  int off = 0, nd = 0;
  for (int e = 0; e < NEXP; e++) {
    offsets[e] = off;
    cursors[e] = 0;
    int n = counts[e];
    for (int s = 0; s < n; s += BM) {
      descs[nd].row_start = off + s;
      descs[nd].nrows = (n - s < BM) ? (n - s) : BM;
      descs[nd].e = e; nd++;
    }
    off += n;
  }
  for (int i = 0; i < 32; i++) {
    descs[nd].row_start = 2 * T_TOK + i * BM; descs[nd].nrows = BM; descs[nd].e = NEXP; nd++;
  }
  for (; nd < NDESC; nd++) descs[nd].nrows = 0;
}

// ---------------- scatter: token -> assignment slots ----------------
__global__ void k_scatter(const int* __restrict__ tk_idx, const int* __restrict__ offsets,
                          int* __restrict__ cursors, int* __restrict__ tok,
                          int* __restrict__ pos) {
  int t = blockIdx.x * 256 + threadIdx.x;
  if (t >= T_TOK) return;
  #pragma unroll
  for (int k = 0; k < 2; k++) {
    int e = tk_idx[t * 2 + k];
    int pp = atomicAdd(&cursors[e], 1);
    int a = offsets[e] + pp;
    tok[a] = t;
    pos[t * 2 + k] = a;
  }
  tok[2 * T_TOK + t] = t;   // shared-expert identity rows
}

// ---------------- GEMM1: gu[rows][4096] = [Xrows @ WgT^T | Xrows @ WuT^T] ----------------
__global__ __launch_bounds__(256, 2) void k_gemm1(
    const u16* __restrict__ Xb, const u16* __restrict__ WgT, const u16* __restrict__ WuT,
    const u16* __restrict__ WgTs, const u16* __restrict__ WuTs,
    const int* __restrict__ tok, const Desc* __restrict__ descs, u16* __restrict__ gu) {
  __shared__ u16 As[BM * BK];
  __shared__ u16 Bs[BM * BK];
  const Desc d = descs[blockIdx.y];
  if (d.nrows <= 0) return;
  const int is_up = (int)(blockIdx.x >> 4);
  const int n0 = (int)(blockIdx.x & 15) * 128;
  const u16* BT = (d.e == NEXP) ? (is_up ? WuTs : WgTs)
                                : ((is_up ? WuT : WgT) + (size_t)d.e * F_DIM * D_DIM);
  const int tid = threadIdx.x;
  const int w = tid >> 6, lane = tid & 63;

  const u16* pA[4]; const u16* pB[4]; unsigned aoff[4];
  #pragma unroll
  for (int j = 0; j < 4; j++) {
    const int chunk = w * 4 + j;
    const int row = chunk * 8 + (lane >> 3);
    const int col = (lane & 7) * 8;
    const int tr = tok[d.row_start + row];
    pA[j] = Xb + (size_t)tr * D_DIM + col;
    pB[j] = BT + (size_t)(n0 + row) * D_DIM + col;
    aoff[j] = (unsigned)chunk * 1024u;
  }

  f32x4 acc[4][4];
  #pragma unroll
  for (int m = 0; m < 4; m++)
    #pragma unroll
    for (int n = 0; n < 4; n++) acc[m][n] = (f32x4)0.f;

  const int wr = w >> 1, wc = w & 1;
  const u16* aP = As + (wr * 64 + (lane & 15)) * BK + (lane >> 4) * 8;
  const u16* bP = Bs + (wc * 64 + (lane & 15)) * BK + (lane >> 4) * 8;

  for (int k0 = 0; k0 < D_DIM; k0 += BK) {
    #pragma unroll
    for (int j = 0; j < 4; j++) {
      GLD16(pA[j] + k0, (char*)As + aoff[j]);
      GLD16(pB[j] + k0, (char*)Bs + aoff[j]);
    }
    __syncthreads();
    #pragma unroll
    for (int ks = 0; ks < 2; ks++) {
      bf16x8 af[4], bfr[4];
      #pragma unroll
      for (int m = 0; m < 4; m++) af[m] = *(const bf16x8*)(aP + m * 16 * BK + ks * 32);
      #pragma unroll
      for (int n = 0; n < 4; n++) bfr[n] = *(const bf16x8*)(bP + n * 16 * BK + ks * 32);
      #pragma unroll
      for (int m = 0; m < 4; m++)
        #pragma unroll
        for (int n = 0; n < 4; n++)
          acc[m][n] = __builtin_amdgcn_mfma_f32_16x16x32_bf16(af[m], bfr[n], acc[m][n], 0, 0, 0);
    }
    __syncthreads();
  }

  const int colbase = (is_up ? F_DIM : 0) + n0 + wc * 64;
  #pragma unroll
  for (int m = 0; m < 4; m++) {
    const int rbase = wr * 64 + m * 16 + ((lane >> 4) << 2);
    #pragma unroll
    for (int n = 0; n < 4; n++) {
      const int col = colbase + n * 16 + (lane & 15);
      #pragma unroll
      for (int j = 0; j < 4; j++) {
        const int r = rbase + j;
        if (r < d.nrows)
          gu[(size_t)(d.row_start + r) * (2 * F_DIM) + col] = f2bf(acc[m][n][j]);
      }
    }
  }
}

// ---------------- SwiGLU in place: gu[:, 0:2048] = silu(g) * u ----------------
__global__ void k_swiglu(u16* __restrict__ gu) {
  const int row = blockIdx.x;
  const int f0 = threadIdx.x * 8;
  u16* base = gu + (size_t)row * (2 * F_DIM);
  uint4 gv = *(const uint4*)(base + f0);
  uint4 uv = *(const uint4*)(base + F_DIM + f0);
  const u16* g = (const u16*)&gv;
  const u16* u = (const u16*)&uv;
  u16 o[8];
  #pragma unroll
  for (int i = 0; i < 8; i++) {
    float gf = bf2f(g[i]), uf = bf2f(u[i]);
    float h = gf / (1.f + expf(-gf)) * uf;
    o[i] = f2bf(h);
  }
  *(uint4*)(base + f0) = *(const uint4*)o;
}

// ---------------- GEMM2: eout/out = H @ Wd ----------------
__global__ __launch_bounds__(256, 2) void k_gemm2(
    const u16* __restrict__ gu, const u16* __restrict__ WdT, const u16* __restrict__ WdTs,
    const Desc* __restrict__ descs, float* __restrict__ eout, float* __restrict__ out) {
  __shared__ u16 As[BM * BK];
  __shared__ u16 Bs[BM * BK];
  const Desc d = descs[blockIdx.y];
  if (d.nrows <= 0) return;
  const int n0 = (int)blockIdx.x * 128;
  const u16* BT = (d.e == NEXP) ? WdTs : (WdT + (size_t)d.e * D_DIM * F_DIM);
  const int tid = threadIdx.x;
  const int w = tid >> 6, lane = tid & 63;

  const u16* pA[4]; const u16* pB[4]; unsigned aoff[4];
  #pragma unroll
  for (int j = 0; j < 4; j++) {
    const int chunk = w * 4 + j;
    const int row = chunk * 8 + (lane >> 3);
    const int col = (lane & 7) * 8;
    pA[j] = gu + (size_t)(d.row_start + row) * (2 * F_DIM) + col;
    pB[j] = BT + (size_t)(n0 + row) * F_DIM + col;
    aoff[j] = (unsigned)chunk * 1024u;
  }

  f32x4 acc[4][4];
  #pragma unroll
  for (int m = 0; m < 4; m++)
    #pragma unroll
    for (int n = 0; n < 4; n++) acc[m][n] = (f32x4)0.f;

  const int wr = w >> 1, wc = w & 1;
  const u16* aP = As + (wr * 64 + (lane & 15)) * BK + (lane >> 4) * 8;
  const u16* bP = Bs + (wc * 64 + (lane & 15)) * BK + (lane >> 4) * 8;

  for (int k0 = 0; k0 < F_DIM; k0 += BK) {
    #pragma unroll
    for (int j = 0; j < 4; j++) {
      GLD16(pA[j] + k0, (char*)As + aoff[j]);
      GLD16(pB[j] + k0, (char*)Bs + aoff[j]);
    }
    __syncthreads();
    #pragma unroll
    for (int ks = 0; ks < 2; ks++) {
      bf16x8 af[4], bfr[4];
      #pragma unroll
      for (int m = 0; m < 4; m++) af[m] = *(const bf16x8*)(aP + m * 16 * BK + ks * 32);
      #pragma unroll
      for (int n = 0; n < 4; n++) bfr[n] = *(const bf16x8*)(bP + n * 16 * BK + ks * 32);
      #pragma unroll
      for (int m = 0; m < 4; m++)
        #pragma unroll
        for (int n = 0; n < 4; n++)
          acc[m][n] = __builtin_amdgcn_mfma_f32_16x16x32_bf16(af[m], bfr[n], acc[m][n], 0, 0, 0);
    }
    __syncthreads();
  }

  #pragma unroll
  for (int m = 0; m < 4; m++) {
    const int rbase = wr * 64 + m * 16 + ((lane >> 4) << 2);
    #pragma unroll
    for (int n = 0; n < 4; n++) {
      const int col = n0 + wc * 64 + n * 16 + (lane & 15);
      #pragma unroll
      for (int j = 0; j < 4; j++) {
        const int r = rbase + j;
        if (r < d.nrows) {
          const int grow = d.row_start + r;
          float v = acc[m][n][j];
          if (d.e == NEXP) out[(size_t)(grow - 2 * T_TOK) * D_DIM + col] = v;
          else             eout[(size_t)grow * D_DIM + col] = v;
        }
      }
    }
  }
}

// ---------------- combine: out[t] += w0*eout[p0] + w1*eout[p1] ----------------
__global__ void k_combine(const float* __restrict__ eout, const int* __restrict__ pos,
                          const float* __restrict__ tk_w, float* __restrict__ out) {
  const int t = blockIdx.x;
  const int dc = threadIdx.x * 4;
  const int p0 = pos[t * 2], p1 = pos[t * 2 + 1];
  const float w0 = tk_w[t * 2], w1 = tk_w[t * 2 + 1];
  float* op = out + (size_t)t * D_DIM + dc;
  float4 o = *(float4*)op;
  float4 a = *(const float4*)(eout + (size_t)p0 * D_DIM + dc);
  float4 b = *(const float4*)(eout + (size_t)p1 * D_DIM + dc);
  o.x += w0 * a.x + w1 * b.x;
  o.y += w0 * a.y + w1 * b.y;
  o.z += w0 * a.z + w1 * b.z;
  o.w += w0 * a.w + w1 * b.w;
  *(float4*)op = o;
}

extern "C" void kernel_launch(void* const* d_in, const int* in_sizes, int n_in,
                              void* d_out, int out_size, void* d_ws, size_t ws_size,
                              hipStream_t stream) {
  const float* X    = (const float*)d_in[0];
  const float* Wr   = (const float*)d_in[1];
  const float* Wg_s = (const float*)d_in[2];
  const float* Wu_s = (const float*)d_in[3];
  const float* Wd_s = (const float*)d_in[4];
  const float* Wg   = (const float*)d_in[5];
  const float* Wu   = (const float*)d_in[6];
  const float* Wd   = (const float*)d_in[7];
  float* out = (float*)d_out;

  char* ws = (char*)d_ws;
  size_t o = 0;
  auto alloc = [&](size_t bytes) -> void* {
    void* p = ws + o;
    o += (bytes + 255) & ~(size_t)255;
    return p;
  };
  u16* Xb    = (u16*)alloc((size_t)T_TOK * D_DIM * 2);
  u16* WgTs  = (u16*)alloc((size_t)F_DIM * D_DIM * 2);
  u16* WuTs  = (u16*)alloc((size_t)F_DIM * D_DIM * 2);
  u16* WdTs  = (u16*)alloc((size_t)D_DIM * F_DIM * 2);
  u16* WgT   = (u16*)alloc((size_t)NEXP * F_DIM * D_DIM * 2);
  u16* WuT   = (u16*)alloc((size_t)NEXP * F_DIM * D_DIM * 2);
  u16* WdT   = (u16*)alloc((size_t)NEXP * D_DIM * F_DIM * 2);
  u16* gu    = (u16*)alloc((size_t)(3 * T_TOK) * (2 * F_DIM) * 2);
  float* eout= (float*)alloc((size_t)(2 * T_TOK) * D_DIM * 4);
  int* tk_idx= (int*)alloc((size_t)T_TOK * 2 * 4);
  float* tk_w= (float*)alloc((size_t)T_TOK * 2 * 4);
  int* pos   = (int*)alloc((size_t)T_TOK * 2 * 4);
  int* tok   = (int*)alloc((size_t)(3 * T_TOK) * 4);
  int* meta  = (int*)alloc(256);           // counts[0:8], offsets[8:16], cursors[16:24]
  Desc* descs= (Desc*)alloc(NDESC * sizeof(Desc));
  if (o > ws_size) return;  // insufficient workspace — fail loudly

  int* counts = meta, *offsets = meta + 8, *cursors = meta + 16;

  k_zmeta<<<1, 64, 0, stream>>>(meta);
  k_convert<<<(T_TOK * D_DIM / 8 + 255) / 256, 256, 0, stream>>>(X, Xb, T_TOK * D_DIM / 8);
  k_tconv<<<dim3(D_DIM / 64, F_DIM / 64, 1), 256, 0, stream>>>(Wg_s, WgTs, D_DIM, F_DIM);
  k_tconv<<<dim3(D_DIM / 64, F_DIM / 64, 1), 256, 0, stream>>>(Wu_s, WuTs, D_DIM, F_DIM);
  k_tconv<<<dim3(F_DIM / 64, D_DIM / 64, 1), 256, 0, stream>>>(Wd_s, WdTs, F_DIM, D_DIM);
  k_tconv<<<dim3(D_DIM / 64, F_DIM / 64, NEXP), 256, 0, stream>>>(Wg, WgT, D_DIM, F_DIM);
  k_tconv<<<dim3(D_DIM / 64, F_DIM / 64, NEXP), 256, 0, stream>>>(Wu, WuT, D_DIM, F_DIM);
  k_tconv<<<dim3(F_DIM / 64, D_DIM / 64, NEXP), 256, 0, stream>>>(Wd, WdT, F_DIM, D_DIM);
  k_router<<<T_TOK / 4, 256, 0, stream>>>(X, Wr, tk_idx, tk_w, counts);
  k_scan<<<1, 64, 0, stream>>>(counts, offsets, cursors, descs);
  k_scatter<<<T_TOK / 256, 256, 0, stream>>>(tk_idx, offsets, cursors, tok, pos);
  k_gemm1<<<dim3(32, NDESC), 256, 0, stream>>>(Xb, WgT, WuT, WgTs, WuTs, tok, descs, gu);
  k_swiglu<<<3 * T_TOK, 256, 0, stream>>>(gu);
  k_gemm2<<<dim3(8, NDESC), 256, 0, stream>>>(gu, WdT, WdTs, descs, eout, out);
  k_combine<<<T_TOK, 256, 0, stream>>>(eout, pos, tk_w, out);
}